// Round 9
// baseline (813.612 us; speedup 1.0000x reference)
//
#include <hip/hip_runtime.h>

#define B_  32
#define N_  512
#define E_  32768
#define H_  64
#define L_  2
#define T_  2
#define IN_ 8

typedef __attribute__((ext_vector_type(4))) float f32x4;
typedef __attribute__((ext_vector_type(8))) short bf16x8;
typedef __attribute__((ext_vector_type(4))) short s16x4;
typedef __attribute__((ext_vector_type(4))) unsigned u32x4;

__device__ __forceinline__ short f2bf(float f){
  unsigned u = __float_as_uint(f);
  u += 0x7FFFu + ((u >> 16) & 1u);          // RNE round to bf16
  return (short)(u >> 16);
}
__device__ __forceinline__ float bf2f(short s){
  return __uint_as_float(((unsigned)(unsigned short)s) << 16);
}
__device__ __forceinline__ bf16x8 pack8(f32x4 a, f32x4 b){
  bf16x8 r;
  r[0]=f2bf(a[0]); r[1]=f2bf(a[1]); r[2]=f2bf(a[2]); r[3]=f2bf(a[3]);
  r[4]=f2bf(b[0]); r[5]=f2bf(b[1]); r[6]=f2bf(b[2]); r[7]=f2bf(b[3]);
  return r;
}
__device__ __forceinline__ unsigned cvt_pk_bf16(float lo, float hi){
  unsigned r;
  asm("v_cvt_pk_bf16_f32 %0, %1, %2" : "=v"(r) : "v"(lo), "v"(hi));
  return r;
}
__device__ __forceinline__ bf16x8 pack8cvt(f32x4 a, f32x4 b){
  union { u32x4 u; bf16x8 h; } r;
  r.u[0] = cvt_pk_bf16(a[0], a[1]);
  r.u[1] = cvt_pk_bf16(a[2], a[3]);
  r.u[2] = cvt_pk_bf16(b[0], b[1]);
  r.u[3] = cvt_pk_bf16(b[2], b[3]);
  return r.h;
}
__device__ __forceinline__ float lo16f(unsigned u){ return __uint_as_float(u << 16); }
__device__ __forceinline__ float hi16f(unsigned u){ return __uint_as_float(u & 0xffff0000u); }

__device__ __forceinline__ float fast_tanh(float x){
  float e = __builtin_amdgcn_exp2f(x * 2.8853900817779268f);  // e^(2x)
  float r = __builtin_amdgcn_rcpf(e + 1.0f);
  return __builtin_fmaf(-2.0f, r, 1.0f);
}
__device__ __forceinline__ float fast_sigm(float x){
  return __builtin_amdgcn_rcpf(1.0f + __builtin_amdgcn_exp2f(x * -1.4426950408889634f));
}
__device__ __forceinline__ float softplus_f(float x){
  return fmaxf(x, 0.0f) + log1pf(__expf(-fabsf(x)));
}

// ---------------- edges: hard gumbel-softmax (forward value == one-hot) ----
__global__ void k_edges(const float* __restrict__ logits, const float* __restrict__ gum,
                        float* __restrict__ edges_out, unsigned char* __restrict__ type_out){
  int i = blockIdx.x * 256 + threadIdx.x;   // [0, B*E)
  if(i >= B_ * E_) return;
  float l0 = logits[2*i]   + gum[2*i];
  float l1 = logits[2*i+1] + gum[2*i+1];
  int t = (l1 > l0) ? 1 : 0;                // argmax, first-wins on tie
  edges_out[2*i]   = t ? 0.f : 1.f;
  edges_out[2*i+1] = t ? 1.f : 0.f;
  type_out[i] = (unsigned char)t;
}

// ---------------- batch-independent recv CSR (row_start, deg) --------------
__global__ void k_hist(const int* __restrict__ recvE, int* __restrict__ hist){
  int e = blockIdx.x * 256 + threadIdx.x;
  if(e < E_) atomicAdd(&hist[recvE[e]], 1);
}
__global__ void k_scan(const int* __restrict__ hist, int* __restrict__ row_start,
                       float* __restrict__ deg){
  __shared__ int a[512], bbuf[512];
  int t = threadIdx.x;
  int h = hist[t];
  a[t] = h;
  __syncthreads();
  int* cur = a; int* nxt = bbuf;
  for(int off = 1; off < 512; off <<= 1){
    int v = cur[t] + (t >= off ? cur[t - off] : 0);
    nxt[t] = v;
    __syncthreads();
    int* tmp = cur; cur = nxt; nxt = tmp;
  }
  row_start[t] = cur[t] - h;                // exclusive
  if(t == 0) row_start[512] = E_;
  deg[t] = (h == 0) ? 1.0f : (float)h;
}

// ---------------- per-batch (type, recv) CSR build -------------------------
__global__ void k_hist2(const int* __restrict__ recvE, const unsigned char* __restrict__ typ,
                        int* __restrict__ n0){
  __shared__ int lh[512];
  int b = blockIdx.y, tid = threadIdx.x;
  lh[tid] = 0; lh[tid + 256] = 0;
  __syncthreads();
  int e0 = blockIdx.x * 2048;
  for(int k = 0; k < 8; ++k){
    int e = e0 + k*256 + tid;
    if(typ[(size_t)b*E_ + e] == 0) atomicAdd(&lh[recvE[e]], 1);
  }
  __syncthreads();
  if(lh[tid])       atomicAdd(&n0[b*512 + tid],       lh[tid]);
  if(lh[tid + 256]) atomicAdd(&n0[b*512 + tid + 256], lh[tid + 256]);
}
__global__ void k_scan2(const int* __restrict__ n0, const int* __restrict__ row_start,
                        int* __restrict__ stt){
  __shared__ int a[512], bbuf[512];
  __shared__ int tot;
  int b = blockIdx.x, t = threadIdx.x;
  int h = n0[b*512 + t];
  a[t] = h;
  __syncthreads();
  int* cur = a; int* nxt = bbuf;
  for(int off = 1; off < 512; off <<= 1){
    int v = cur[t] + (t >= off ? cur[t - off] : 0);
    nxt[t] = v;
    __syncthreads();
    int* tmp = cur; cur = nxt; nxt = tmp;
  }
  if(t == 511) tot = cur[511];
  __syncthreads();
  int excl = cur[t] - h;
  stt[(b*2    )*513 + t] = excl;                       // type-0 run start
  stt[(b*2 + 1)*513 + t] = tot + row_start[t] - excl;  // type-1 run start
  if(t == 0){ stt[(b*2)*513 + 512] = tot; stt[(b*2+1)*513 + 512] = E_; }
}
__global__ void k_perm2(const int* __restrict__ recvE, const unsigned char* __restrict__ typ,
                        const int* __restrict__ stt, int* __restrict__ cur0,
                        int* __restrict__ cur1, unsigned short* __restrict__ perm2){
  int i = blockIdx.x * 256 + threadIdx.x;   // [0, B*E)
  int b = i >> 15, e = i & (E_ - 1);
  int r = recvE[e];
  int pos;
  if(typ[i] == 0) pos = stt[(b*2  )*513 + r] + atomicAdd(&cur0[b*512 + r], 1);
  else            pos = stt[(b*2+1)*513 + r] + atomicAdd(&cur1[b*512 + r], 1);
  perm2[(size_t)b*E_ + pos] = (unsigned short)e;
}

// ---------------- per-node GEMM1 hoist ------------------------------------
// P[b][n][slot][64] bf16, slot = {t0_recv(+b1), t1_recv(+b1), t0_send, t1_send}
__launch_bounds__(256, 2)
__global__ void k_prep(const float* __restrict__ hid,
                       const float* __restrict__ W1, const float* __restrict__ b1,
                       unsigned short* __restrict__ P, int layer){
  __shared__ __align__(16) short WT[256 * 64];   // [col][f] bf16, XOR-swizzled
  __shared__ float bias[256];
  __shared__ float hidl[32 * 64];                // 32 nodes staged f32 (8 KB)

  const int tid = threadIdx.x;
  const int b   = blockIdx.y;
  const int nbase = blockIdx.x * 32;
  const float* W1k = W1 + layer * (T_ * H_ * 2 * H_);

  { // stage WT: col = tid -> slot = col>>6, h = col&63; src W1k[t][h][prt*64 + f]
    int col = tid, slot = col >> 6, h = col & 63;
    int t = slot & 1, prt = slot >> 1;
    const float* src = W1k + t*8192 + h*128 + prt*64;
#pragma unroll
    for(int u = 0; u < 8; ++u){
      bf16x8 v = pack8(*(const f32x4*)(src + u*8), *(const f32x4*)(src + u*8 + 4));
      int bo = col*128 + ((u*16) ^ ((col & 7) << 4));
      *(bf16x8*)((char*)WT + bo) = v;
    }
    bias[col] = (slot < 2) ? b1[layer*128 + t*64 + h] : 0.0f;
  }
  { // stage 32 nodes of hid: 2048 f32 = 512 f32x4, 2 per thread
    const float* src = hid + ((size_t)b*N_ + nbase)*H_;
    ((f32x4*)hidl)[tid]       = ((const f32x4*)src)[tid];
    ((f32x4*)hidl)[tid + 256] = ((const f32x4*)src)[tid + 256];
  }
  __syncthreads();

  const int col = tid;
  for(int n = 0; n < 32; ++n){
    const float* hrow = hidl + n*64;
    float acc = bias[col];
#pragma unroll
    for(int u = 0; u < 8; ++u){
      int bo = col*128 + ((u*16) ^ ((col & 7) << 4));
      bf16x8 wv = *(const bf16x8*)((const char*)WT + bo);
#pragma unroll
      for(int i = 0; i < 8; ++i) acc += hrow[u*8 + i] * bf2f(wv[i]);
    }
    P[(((size_t)b*N_ + nbase + n) << 8) + col] = (unsigned short)f2bf(acc);
  }
}

// ---------------- edge-MLP message passing (GEMM2 only, MFMA) --------------
// Round-7 structure (2 barriers/tile, loads consumed in-region).
__launch_bounds__(256, 6)
__global__ void k_msg(const unsigned short* __restrict__ P,
                      const float* __restrict__ W2, const float* __restrict__ b2,
                      const int* __restrict__ recvE, const int* __restrict__ sendE,
                      const unsigned short* __restrict__ perm2,
                      const int* __restrict__ stt, const float* __restrict__ deg,
                      float* __restrict__ agg, int layer){
  __shared__ __align__(16) short m1_lds[64 * 64];   // [e][h] bf16, XOR-swizzled
  __shared__ float acc[8][64];
  __shared__ float b2_lds[128];
  __shared__ short rl_lds[64];

  const int tid  = threadIdx.x;
  const int w    = tid >> 6, lane = tid & 63;
  const int l15  = lane & 15, l4 = lane >> 4;
  const int b    = blockIdx.y;
  const int nodeBase = blockIdx.x * 8;

  const float* W2k = W2 + layer * (T_ * H_ * H_);

  if(tid < 128) b2_lds[tid] = b2[layer*128 + tid];
  acc[tid >> 6][tid & 63] = 0.0f;
  { int t2 = tid + 256; acc[t2 >> 6][t2 & 63] = 0.0f; }

  // Both types' B fragments for GEMM2, 16 output columns per wave.
  bf16x8 B2f[2][2];
#pragma unroll
  for(int t = 0; t < 2; ++t)
#pragma unroll
    for(int ks = 0; ks < 2; ++ks){
      const float* p = W2k + (t*64 + w*16 + l15)*64 + ks*32 + l4*8;
      B2f[t][ks] = pack8(*(const f32x4*)p, *(const f32x4*)(p+4));
    }

  const int gcol = w*16 + l15;
  const unsigned short* permB = perm2 + (size_t)b * E_;
  const int* sttB = stt + b*2*513;

#pragma unroll
  for(int seg = 0; seg < 2; ++seg){
    const int s0 = sttB[seg*513 + nodeBase];
    const int s1 = sttB[seg*513 + nodeBase + 8];
    const int ntiles = (s1 - s0 + 63) >> 6;
    for(int it = 0; it < ntiles; ++it){
      const int sbase = s0 + it*64;
      { // ---- stage m1 = tanh(P_r[recv] + P_s[send]); 4 thr/edge, 16 h each
        int el = tid >> 2, part = tid & 3;
        int s = sbase + el;
        int h0 = part * 16;
        int bo0 = el*128 + ((h0*2)      ^ ((el & 7) << 4));
        int bo1 = el*128 + ((h0*2 + 16) ^ ((el & 7) << 4));
        if(s < s1){
          int eid = permB[s];
          int rv = recvE[eid], sd = sendE[eid];
          if(part == 0) rl_lds[el] = (short)(rv - nodeBase);
          const unsigned short* pr = P + (((size_t)b*N_ + rv) << 8) + seg*64 + h0;
          const unsigned short* ps = P + (((size_t)b*N_ + sd) << 8) + (2+seg)*64 + h0;
          u32x4 R0 = *(const u32x4*)pr, R1 = *(const u32x4*)(pr + 8);
          u32x4 S0 = *(const u32x4*)ps, S1 = *(const u32x4*)(ps + 8);
          unsigned q0[4], q1[4];
#pragma unroll
          for(int j = 0; j < 4; ++j){
            unsigned t0 = (unsigned)(unsigned short)f2bf(fast_tanh(lo16f(R0[j]) + lo16f(S0[j])));
            unsigned t1 = (unsigned)(unsigned short)f2bf(fast_tanh(hi16f(R0[j]) + hi16f(S0[j])));
            q0[j] = t0 | (t1 << 16);
            unsigned t2 = (unsigned)(unsigned short)f2bf(fast_tanh(lo16f(R1[j]) + lo16f(S1[j])));
            unsigned t3 = (unsigned)(unsigned short)f2bf(fast_tanh(hi16f(R1[j]) + hi16f(S1[j])));
            q1[j] = t2 | (t3 << 16);
          }
          *(u32x4*)((char*)m1_lds + bo0) = (u32x4){q0[0], q0[1], q0[2], q0[3]};
          *(u32x4*)((char*)m1_lds + bo1) = (u32x4){q1[0], q1[1], q1[2], q1[3]};
        }else{
          if(part == 0) rl_lds[el] = 255;
          u32x4 z = {};
          *(u32x4*)((char*)m1_lds + bo0) = z;
          *(u32x4*)((char*)m1_lds + bo1) = z;
        }
      }
      __syncthreads();

      // ---- GEMM2 (16 cols/wave, type = seg), K=64
      f32x4 C2[4];
      { float bv = b2_lds[seg*64 + gcol];
#pragma unroll
        for(int ef = 0; ef < 4; ++ef) C2[ef] = (f32x4){bv, bv, bv, bv}; }
#pragma unroll
      for(int ks = 0; ks < 2; ++ks){
#pragma unroll
        for(int ef = 0; ef < 4; ++ef){
          int e = ef*16 + l15;
          int byteoff = e*128 + (((ks*32 + l4*8)*2) ^ ((e & 7) << 4));
          bf16x8 A = *(const bf16x8*)((const char*)m1_lds + byteoff);
          C2[ef] = __builtin_amdgcn_mfma_f32_16x16x32_bf16(A, B2f[seg][ks], C2[ef], 0, 0, 0);
        }
      }
      // ---- tanh, run-merge by rl (sorted within segment), LDS accumulate
      {
        int prl = -1; float pend = 0.f;
#pragma unroll
        for(int ef = 0; ef < 4; ++ef){
          s16x4 rl4 = *(const s16x4*)&rl_lds[ef*16 + l4*4];
#pragma unroll
          for(int r = 0; r < 4; ++r){
            int rl = rl4[r];
            if(rl != prl){
              if(prl >= 0) atomicAdd(&acc[prl][gcol], pend);
              pend = 0.f;
              prl = (rl == 255) ? -1 : rl;
            }
            if(rl != 255) pend += fast_tanh(C2[ef][r]);
          }
        }
        if(prl >= 0) atomicAdd(&acc[prl][gcol], pend);
      }
      __syncthreads();
    }
  }

  // ---- final: agg[b][node][g] = acc * 0.5 / deg   (0.5 = 1/T norm folded)
#pragma unroll
  for(int q = 0; q < 2; ++q){
    int idx = tid + q*256;
    int rl = idx >> 6, g = idx & 63;
    int node = nodeBase + rl;
    agg[(((size_t)b*N_ + node) << 6) + g] = acc[rl][g] * 0.5f / deg[node];
  }
}

// ---------------- GRU-style node update (32 ids/block) ---------------------
// Weights in [g][f] bf16 XOR-swizzled LDS, read via ds_read_b128 (8 f/read).
__launch_bounds__(256, 2)
__global__ void k_gru(const float* __restrict__ x, const float* __restrict__ hid,
                      const float* __restrict__ agg0, const float* __restrict__ agg1,
                      const float* __restrict__ Whr, const float* __restrict__ Whi,
                      const float* __restrict__ Whh,
                      const float* __restrict__ Wir, const float* __restrict__ bir,
                      const float* __restrict__ Wii, const float* __restrict__ bii,
                      const float* __restrict__ Win, const float* __restrict__ binw,
                      float* __restrict__ hnew){
  __shared__ __align__(16) short Wr[64*128], Wi[64*128], Wh[64*128]; // [g][f] bf16 swz
  __shared__ float WxT[3][8*64];                              // [j][g]
  __shared__ float bias[3][64];
  __shared__ __align__(16) float agg_lds[4][128];

  int tid = threadIdx.x;
  { // stage: g = tid&63, quarter q -> f0 = q*32 .. +31  (row = 256B, swizzled)
    int g = tid & 63, q = tid >> 6;
    const float* srcr = Whr + g*128 + q*32;
    const float* srci = Whi + g*128 + q*32;
    const float* srch = Whh + g*128 + q*32;
#pragma unroll
    for(int u = 0; u < 4; ++u){
      int bo = g*256 + ((((q*32 + u*8)*2)) ^ ((g & 7) << 4));
      *(bf16x8*)((char*)Wr + bo) = pack8(*(const f32x4*)(srcr+u*8), *(const f32x4*)(srcr+u*8+4));
      *(bf16x8*)((char*)Wi + bo) = pack8(*(const f32x4*)(srci+u*8), *(const f32x4*)(srci+u*8+4));
      *(bf16x8*)((char*)Wh + bo) = pack8(*(const f32x4*)(srch+u*8), *(const f32x4*)(srch+u*8+4));
    }
  }
  for(int s = tid; s < 512; s += 256){
    int g = s >> 3, j = s & 7;
    WxT[0][j*64+g] = Wir[s]; WxT[1][j*64+g] = Wii[s]; WxT[2][j*64+g] = Win[s];
  }
  if(tid < 64){ bias[0][tid] = bir[tid]; bias[1][tid] = bii[tid]; bias[2][tid] = binw[tid]; }
  __syncthreads();

  int w = tid >> 6, lane = tid & 63;
  for(int j = 0; j < 8; ++j){
    int id = blockIdx.x*32 + j*4 + w;        // [0, B*N)
    size_t base = (size_t)id * 64;
    agg_lds[w][lane]      = agg0[base + lane];  // wave-local, no barrier needed
    agg_lds[w][64 + lane] = agg1[base + lane];

    float ar = bias[0][lane], ai = bias[1][lane], an = bias[2][lane], ah = 0.f;
    const float* xp = x + (size_t)id * 8;
#pragma unroll
    for(int jj = 0; jj < 8; ++jj){
      float xv = xp[jj];
      ar += xv * WxT[0][jj*64+lane];
      ai += xv * WxT[1][jj*64+lane];
      an += xv * WxT[2][jj*64+lane];
    }
#pragma unroll
    for(int f0 = 0; f0 < 128; f0 += 8){
      int bo = lane*256 + ((f0*2) ^ ((lane & 7) << 4));
      u32x4 wr = *(const u32x4*)((const char*)Wr + bo);
      u32x4 wi = *(const u32x4*)((const char*)Wi + bo);
      u32x4 wh = *(const u32x4*)((const char*)Wh + bo);
      f32x4 aLo = *(const f32x4*)&agg_lds[w][f0];
      f32x4 aHi = *(const f32x4*)&agg_lds[w][f0 + 4];
      float av[8] = {aLo[0], aLo[1], aLo[2], aLo[3], aHi[0], aHi[1], aHi[2], aHi[3]};
#pragma unroll
      for(int jj = 0; jj < 4; ++jj){
        ar = __builtin_fmaf(av[2*jj],   lo16f(wr[jj]), ar);
        ar = __builtin_fmaf(av[2*jj+1], hi16f(wr[jj]), ar);
        ai = __builtin_fmaf(av[2*jj],   lo16f(wi[jj]), ai);
        ai = __builtin_fmaf(av[2*jj+1], hi16f(wi[jj]), ai);
        ah = __builtin_fmaf(av[2*jj],   lo16f(wh[jj]), ah);
        ah = __builtin_fmaf(av[2*jj+1], hi16f(wh[jj]), ah);
      }
    }
    float r  = fast_sigm(ar);
    float ii = fast_sigm(ai);
    float ng = fast_tanh(an + r * ah);
    float ho = hid[base + lane];
    hnew[base + lane] = (1.0f - ii) * ng + ii * ho;
  }
}

// ---------------- pred = Wm2 @ relu(Wm1 @ hnew + bm1) + bm2 (32 ids/block) -
// Weights [g][h] bf16 XOR-swizzled, ds_read_b128. Writes flat bf16 [B][32768].
__launch_bounds__(256, 2)
__global__ void k_pred(const float* __restrict__ hnew,
                       const float* __restrict__ Wm1, const float* __restrict__ bm1,
                       const float* __restrict__ Wm2, const float* __restrict__ bm2,
                       unsigned short* __restrict__ flatbf){
  __shared__ __align__(16) short W1T[64*64], W2T[64*64];  // [g][h] bf16 swz, row 128B
  __shared__ float bias1[64], bias2[64];
  __shared__ __align__(16) float h_lds[4][64], t_lds[4][64];
  int tid = threadIdx.x;
  { // stage: g = tid&63, quarter q -> h0 = q*16 .. +15
    int g = tid & 63, q = tid >> 6;
    const float* s1 = Wm1 + g*64 + q*16;
    const float* s2 = Wm2 + g*64 + q*16;
#pragma unroll
    for(int u = 0; u < 2; ++u){
      int bo = g*128 + ((((q*16 + u*8)*2)) ^ ((g & 7) << 4));
      *(bf16x8*)((char*)W1T + bo) = pack8(*(const f32x4*)(s1+u*8), *(const f32x4*)(s1+u*8+4));
      *(bf16x8*)((char*)W2T + bo) = pack8(*(const f32x4*)(s2+u*8), *(const f32x4*)(s2+u*8+4));
    }
  }
  if(tid < 64){ bias1[tid] = bm1[tid]; bias2[tid] = bm2[tid]; }
  __syncthreads();

  int w = tid >> 6, lane = tid & 63;
  for(int j = 0; j < 8; ++j){
    int id = blockIdx.x*32 + j*4 + w;
    size_t base = (size_t)id * 64;
    h_lds[w][lane] = hnew[base + lane];
    float a = bias1[lane];
#pragma unroll
    for(int h0 = 0; h0 < 64; h0 += 8){
      int bo = lane*128 + ((h0*2) ^ ((lane & 7) << 4));
      u32x4 w1 = *(const u32x4*)((const char*)W1T + bo);
      f32x4 hLo = *(const f32x4*)&h_lds[w][h0];
      f32x4 hHi = *(const f32x4*)&h_lds[w][h0 + 4];
      float hv[8] = {hLo[0], hLo[1], hLo[2], hLo[3], hHi[0], hHi[1], hHi[2], hHi[3]};
#pragma unroll
      for(int jj = 0; jj < 4; ++jj){
        a = __builtin_fmaf(hv[2*jj],   lo16f(w1[jj]), a);
        a = __builtin_fmaf(hv[2*jj+1], hi16f(w1[jj]), a);
      }
    }
    a = fmaxf(a, 0.0f);
    t_lds[w][lane] = a;
    float p = bias2[lane];
#pragma unroll
    for(int h0 = 0; h0 < 64; h0 += 8){
      int bo = lane*128 + ((h0*2) ^ ((lane & 7) << 4));
      u32x4 w2 = *(const u32x4*)((const char*)W2T + bo);
      f32x4 tLo = *(const f32x4*)&t_lds[w][h0];
      f32x4 tHi = *(const f32x4*)&t_lds[w][h0 + 4];
      float tv[8] = {tLo[0], tLo[1], tLo[2], tLo[3], tHi[0], tHi[1], tHi[2], tHi[3]};
#pragma unroll
      for(int jj = 0; jj < 4; ++jj){
        p = __builtin_fmaf(tv[2*jj],   lo16f(w2[jj]), p);
        p = __builtin_fmaf(tv[2*jj+1], hi16f(w2[jj]), p);
      }
    }
    flatbf[base + lane] = (unsigned short)f2bf(p);   // flat[b][n*64+g] bf16
  }
}

// ---------------- k_out: pacc[1536][32] += W[mt]·flat^T, split-K MFMA ------
__launch_bounds__(256, 6)
__global__ void k_out(const float* __restrict__ Wdf, const float* __restrict__ Wloc,
                      const float* __restrict__ Wsc,
                      const unsigned short* __restrict__ flatbf,
                      float* __restrict__ pacc){
  const int bid = blockIdx.x;
  const int mt  = bid >> 5;                  // [0,48) M-tile of 32 rows
  const int kb  = bid & 31;                  // K-chunk of 1024
  const int row0 = mt * 32;                  // global row in [0,1536)
  const int mat  = row0 >> 9;
  const int rloc = row0 & 511;
  const float* W = (mat == 0) ? Wdf : (mat == 1) ? Wloc : Wsc;

  const int tid = threadIdx.x, w = tid >> 6, lane = tid & 63;
  const int l15 = lane & 15, l4 = lane >> 4;
  const float* wp = W + (size_t)(rloc + (w & 1)*16 + l15)*32768 + kb*1024 + l4*8;
  const unsigned short* fp = flatbf + (size_t)((w >> 1)*16 + l15)*32768 + kb*1024 + l4*8;

  f32x4 acc0 = {}, acc1 = {};
#pragma unroll 4
  for(int ks = 0; ks < 32; ks += 2){
    f32x4 a0 = *(const f32x4*)(wp + ks*32);
    f32x4 a1 = *(const f32x4*)(wp + ks*32 + 4);
    bf16x8 Bv0 = *(const bf16x8*)(fp + ks*32);
    f32x4 a2 = *(const f32x4*)(wp + ks*32 + 32);
    f32x4 a3 = *(const f32x4*)(wp + ks*32 + 36);
    bf16x8 Bv1 = *(const bf16x8*)(fp + ks*32 + 32);
    acc0 = __builtin_amdgcn_mfma_f32_16x16x32_bf16(pack8cvt(a0, a1), Bv0, acc0, 0, 0, 0);
    acc1 = __builtin_amdgcn_mfma_f32_16x16x32_bf16(pack8cvt(a2, a3), Bv1, acc1, 0, 0, 0);
  }
  // C/D: col = l15 (batch), row = l4*4 + r (within 16-row half-tile)
#pragma unroll
  for(int r = 0; r < 4; ++r){
    int grow = row0 + (w & 1)*16 + l4*4 + r;
    atomicAdd(&pacc[grow*32 + (w >> 1)*16 + l15], acc0[r] + acc1[r]);
  }
}

// ---------------- k_fin: bias + StudentT transforms ------------------------
__global__ void k_fin(const float* __restrict__ pacc,
                      const float* __restrict__ bdf, const float* __restrict__ bloc,
                      const float* __restrict__ bsc, float* __restrict__ out){
  int i = blockIdx.x*256 + threadIdx.x;      // [0, 49152)
  int mat = i >> 14;
  int rem = i & 16383;                       // b*512 + og
  int b = rem >> 9, og = rem & 511;
  float s = pacc[(mat*512 + og)*32 + b];
  s += (mat == 0 ? bdf : mat == 1 ? bloc : bsc)[og];
  float res = (mat == 0) ? 2.0f + softplus_f(s) : (mat == 1) ? s : softplus_f(s);
  out[i] = res;
}

extern "C" void kernel_launch(void* const* d_in, const int* in_sizes, int n_in,
                              void* d_out, int out_size, void* d_ws, size_t ws_size,
                              hipStream_t stream){
  (void)in_sizes; (void)n_in; (void)out_size; (void)ws_size;
  const float* inputs = (const float*)d_in[0];
  const float* hidden = (const float*)d_in[1];
  const float* elog   = (const float*)d_in[2];
  const float* gum    = (const float*)d_in[3];
  const int*   sendE  = (const int*)  d_in[4];
  const int*   recvE  = (const int*)  d_in[5];
  const float* W1   = (const float*)d_in[6];
  const float* b1   = (const float*)d_in[7];
  const float* W2   = (const float*)d_in[8];
  const float* b2   = (const float*)d_in[9];
  const float* Whr  = (const float*)d_in[10];
  const float* Whi  = (const float*)d_in[11];
  const float* Whh  = (const float*)d_in[12];
  const float* Wir  = (const float*)d_in[13]; const float* bir  = (const float*)d_in[14];
  const float* Wii  = (const float*)d_in[15]; const float* bii  = (const float*)d_in[16];
  const float* Win  = (const float*)d_in[17]; const float* binw = (const float*)d_in[18];
  const float* Wm1  = (const float*)d_in[19]; const float* bm1  = (const float*)d_in[20];
  const float* Wm2  = (const float*)d_in[21]; const float* bm2  = (const float*)d_in[22];
  const float* Wdf  = (const float*)d_in[23]; const float* bdf  = (const float*)d_in[24];
  const float* Wloc = (const float*)d_in[25]; const float* bloc = (const float*)d_in[26];
  const float* Wsc  = (const float*)d_in[27]; const float* bsc  = (const float*)d_in[28];

  float* out       = (float*)d_out;
  float* out_hid   = out + 49152;            // df,loc,scale = 3*16384
  float* out_edges = out + 1097728;          // + B*N*H

  char* ws = (char*)d_ws;
  float* agg0 = (float*)(ws);                               // 4 MB
  float* agg1 = (float*)(ws + 4194304);                     // 4 MB
  unsigned short* P = (unsigned short*)(ws + 8388608);      // 8 MB [B][N][4][64] bf16
  unsigned short* flatbf = (unsigned short*)(ws + 8388608); // 2 MB overlay on P (after k_msg)
  unsigned short* perm2 = (unsigned short*)(ws + 16777216); // 2 MB [B][E]
  unsigned char* typ = (unsigned char*)(ws + 18874368);     // 1 MB [B][E]
  int*   hist      = (int*)(ws + 19922944);                 // 2 KB
  int*   row_start = (int*)(ws + 19924992);                 // 4 KB slot (513 ints)
  float* deg       = (float*)(ws + 19929088);               // 2 KB
  int*   n0        = (int*)(ws + 19931136);                 // 64 KB [B][512]
  int*   cur0      = (int*)(ws + 19996672);                 // 64 KB
  int*   cur1      = (int*)(ws + 20062208);                 // 64 KB
  int*   stt       = (int*)(ws + 20127744);                 // 128.25 KB [B][2][513]
  float* pacc      = agg0;                                  // 196 KB overlay (agg0 dead after k_gru)

  hipMemsetAsync(hist, 0, 2048, stream);
  hipMemsetAsync(n0, 0, 3*65536, stream);    // n0, cur0, cur1 contiguous

  k_edges<<<4096, 256, 0, stream>>>(elog, gum, out_edges, typ);
  k_hist<<<128, 256, 0, stream>>>(recvE, hist);
  k_scan<<<1, 512, 0, stream>>>(hist, row_start, deg);
  k_hist2<<<dim3(16, 32), 256, 0, stream>>>(recvE, typ, n0);
  k_scan2<<<32, 512, 0, stream>>>(n0, row_start, stt);
  k_perm2<<<4096, 256, 0, stream>>>(recvE, typ, stt, cur0, cur1, perm2);

  k_prep<<<dim3(16, 32), 256, 0, stream>>>(hidden, W1, b1, P, 0);
  k_msg<<<dim3(64, 32), 256, 0, stream>>>(P, W2, b2, recvE, sendE,
                                          perm2, stt, deg, agg0, 0);
  k_prep<<<dim3(16, 32), 256, 0, stream>>>(agg0, W1, b1, P, 1);
  k_msg<<<dim3(64, 32), 256, 0, stream>>>(P, W2, b2, recvE, sendE,
                                          perm2, stt, deg, agg1, 1);

  k_gru<<<512, 256, 0, stream>>>(inputs, hidden, agg0, agg1,
                                 Whr, Whi, Whh, Wir, bir, Wii, bii, Win, binw, out_hid);
  k_pred<<<512, 256, 0, stream>>>(out_hid, Wm1, bm1, Wm2, bm2, flatbf);
  hipMemsetAsync(pacc, 0, 1536*32*4, stream);   // agg0 dead after k_gru
  k_out<<<1536, 256, 0, stream>>>(Wdf, Wloc, Wsc, flatbf, pacc);
  k_fin<<<192, 256, 0, stream>>>(pacc, bdf, bloc, bsc, out);
}

// Round 10
// 483.625 us; speedup vs baseline: 1.6823x; 1.6823x over previous
//
#include <hip/hip_runtime.h>

#define B_  32
#define N_  512
#define E_  32768
#define H_  64
#define L_  2
#define T_  2
#define IN_ 8

typedef __attribute__((ext_vector_type(4))) float f32x4;
typedef __attribute__((ext_vector_type(8))) short bf16x8;
typedef __attribute__((ext_vector_type(4))) short s16x4;
typedef __attribute__((ext_vector_type(4))) unsigned u32x4;

__device__ __forceinline__ short f2bf(float f){
  unsigned u = __float_as_uint(f);
  u += 0x7FFFu + ((u >> 16) & 1u);          // RNE round to bf16
  return (short)(u >> 16);
}
__device__ __forceinline__ float bf2f(short s){
  return __uint_as_float(((unsigned)(unsigned short)s) << 16);
}
__device__ __forceinline__ bf16x8 pack8(f32x4 a, f32x4 b){
  bf16x8 r;
  r[0]=f2bf(a[0]); r[1]=f2bf(a[1]); r[2]=f2bf(a[2]); r[3]=f2bf(a[3]);
  r[4]=f2bf(b[0]); r[5]=f2bf(b[1]); r[6]=f2bf(b[2]); r[7]=f2bf(b[3]);
  return r;
}
__device__ __forceinline__ unsigned cvt_pk_bf16(float lo, float hi){
  unsigned r;
  asm("v_cvt_pk_bf16_f32 %0, %1, %2" : "=v"(r) : "v"(lo), "v"(hi));
  return r;
}
__device__ __forceinline__ bf16x8 pack8cvt(f32x4 a, f32x4 b){
  union { u32x4 u; bf16x8 h; } r;
  r.u[0] = cvt_pk_bf16(a[0], a[1]);
  r.u[1] = cvt_pk_bf16(a[2], a[3]);
  r.u[2] = cvt_pk_bf16(b[0], b[1]);
  r.u[3] = cvt_pk_bf16(b[2], b[3]);
  return r.h;
}
__device__ __forceinline__ float lo16f(unsigned u){ return __uint_as_float(u << 16); }
__device__ __forceinline__ float hi16f(unsigned u){ return __uint_as_float(u & 0xffff0000u); }

__device__ __forceinline__ float fast_tanh(float x){
  float e = __builtin_amdgcn_exp2f(x * 2.8853900817779268f);  // e^(2x)
  float r = __builtin_amdgcn_rcpf(e + 1.0f);
  return __builtin_fmaf(-2.0f, r, 1.0f);
}
__device__ __forceinline__ float fast_sigm(float x){
  return __builtin_amdgcn_rcpf(1.0f + __builtin_amdgcn_exp2f(x * -1.4426950408889634f));
}
__device__ __forceinline__ float softplus_f(float x){
  return fmaxf(x, 0.0f) + log1pf(__expf(-fabsf(x)));
}

// ---------------- edges: hard gumbel-softmax (forward value == one-hot) ----
__global__ void k_edges(const float* __restrict__ logits, const float* __restrict__ gum,
                        float* __restrict__ edges_out, unsigned char* __restrict__ type_out){
  int i = blockIdx.x * 256 + threadIdx.x;   // [0, B*E)
  if(i >= B_ * E_) return;
  float l0 = logits[2*i]   + gum[2*i];
  float l1 = logits[2*i+1] + gum[2*i+1];
  int t = (l1 > l0) ? 1 : 0;                // argmax, first-wins on tie
  edges_out[2*i]   = t ? 0.f : 1.f;
  edges_out[2*i+1] = t ? 1.f : 0.f;
  type_out[i] = (unsigned char)t;
}

// ---------------- batch-independent recv CSR (row_start, deg) --------------
__global__ void k_hist(const int* __restrict__ recvE, int* __restrict__ hist){
  int e = blockIdx.x * 256 + threadIdx.x;
  if(e < E_) atomicAdd(&hist[recvE[e]], 1);
}
__global__ void k_scan(const int* __restrict__ hist, int* __restrict__ row_start,
                       float* __restrict__ deg){
  __shared__ int a[512], bbuf[512];
  int t = threadIdx.x;
  int h = hist[t];
  a[t] = h;
  __syncthreads();
  int* cur = a; int* nxt = bbuf;
  for(int off = 1; off < 512; off <<= 1){
    int v = cur[t] + (t >= off ? cur[t - off] : 0);
    nxt[t] = v;
    __syncthreads();
    int* tmp = cur; cur = nxt; nxt = tmp;
  }
  row_start[t] = cur[t] - h;                // exclusive
  if(t == 0) row_start[512] = E_;
  deg[t] = (h == 0) ? 1.0f : (float)h;
}

// ---------------- per-batch (type, recv) CSR build -------------------------
__global__ void k_hist2(const int* __restrict__ recvE, const unsigned char* __restrict__ typ,
                        int* __restrict__ n0){
  __shared__ int lh[512];
  int b = blockIdx.y, tid = threadIdx.x;
  lh[tid] = 0; lh[tid + 256] = 0;
  __syncthreads();
  int e0 = blockIdx.x * 2048;
  for(int k = 0; k < 8; ++k){
    int e = e0 + k*256 + tid;
    if(typ[(size_t)b*E_ + e] == 0) atomicAdd(&lh[recvE[e]], 1);
  }
  __syncthreads();
  if(lh[tid])       atomicAdd(&n0[b*512 + tid],       lh[tid]);
  if(lh[tid + 256]) atomicAdd(&n0[b*512 + tid + 256], lh[tid + 256]);
}
__global__ void k_scan2(const int* __restrict__ n0, const int* __restrict__ row_start,
                        int* __restrict__ stt){
  __shared__ int a[512], bbuf[512];
  __shared__ int tot;
  int b = blockIdx.x, t = threadIdx.x;
  int h = n0[b*512 + t];
  a[t] = h;
  __syncthreads();
  int* cur = a; int* nxt = bbuf;
  for(int off = 1; off < 512; off <<= 1){
    int v = cur[t] + (t >= off ? cur[t - off] : 0);
    nxt[t] = v;
    __syncthreads();
    int* tmp = cur; cur = nxt; nxt = tmp;
  }
  if(t == 511) tot = cur[511];
  __syncthreads();
  int excl = cur[t] - h;
  stt[(b*2    )*513 + t] = excl;                       // type-0 run start
  stt[(b*2 + 1)*513 + t] = tot + row_start[t] - excl;  // type-1 run start
  if(t == 0){ stt[(b*2)*513 + 512] = tot; stt[(b*2+1)*513 + 512] = E_; }
}
__global__ void k_perm2(const int* __restrict__ recvE, const unsigned char* __restrict__ typ,
                        const int* __restrict__ stt, int* __restrict__ cur0,
                        int* __restrict__ cur1, unsigned short* __restrict__ perm2){
  int i = blockIdx.x * 256 + threadIdx.x;   // [0, B*E)
  int b = i >> 15, e = i & (E_ - 1);
  int r = recvE[e];
  int pos;
  if(typ[i] == 0) pos = stt[(b*2  )*513 + r] + atomicAdd(&cur0[b*512 + r], 1);
  else            pos = stt[(b*2+1)*513 + r] + atomicAdd(&cur1[b*512 + r], 1);
  perm2[(size_t)b*E_ + pos] = (unsigned short)e;
}

// ---------------- per-node GEMM1 hoist ------------------------------------
// P[b][n][slot][64] bf16, slot = {t0_recv(+b1), t1_recv(+b1), t0_send, t1_send}
__launch_bounds__(256, 2)
__global__ void k_prep(const float* __restrict__ hid,
                       const float* __restrict__ W1, const float* __restrict__ b1,
                       unsigned short* __restrict__ P, int layer){
  __shared__ __align__(16) short WT[256 * 64];   // [col][f] bf16, XOR-swizzled
  __shared__ float bias[256];
  __shared__ float hidl[32 * 64];                // 32 nodes staged f32 (8 KB)

  const int tid = threadIdx.x;
  const int b   = blockIdx.y;
  const int nbase = blockIdx.x * 32;
  const float* W1k = W1 + layer * (T_ * H_ * 2 * H_);

  { // stage WT: col = tid -> slot = col>>6, h = col&63; src W1k[t][h][prt*64 + f]
    int col = tid, slot = col >> 6, h = col & 63;
    int t = slot & 1, prt = slot >> 1;
    const float* src = W1k + t*8192 + h*128 + prt*64;
#pragma unroll
    for(int u = 0; u < 8; ++u){
      bf16x8 v = pack8(*(const f32x4*)(src + u*8), *(const f32x4*)(src + u*8 + 4));
      int bo = col*128 + ((u*16) ^ ((col & 7) << 4));
      *(bf16x8*)((char*)WT + bo) = v;
    }
    bias[col] = (slot < 2) ? b1[layer*128 + t*64 + h] : 0.0f;
  }
  { // stage 32 nodes of hid: 2048 f32 = 512 f32x4, 2 per thread
    const float* src = hid + ((size_t)b*N_ + nbase)*H_;
    ((f32x4*)hidl)[tid]       = ((const f32x4*)src)[tid];
    ((f32x4*)hidl)[tid + 256] = ((const f32x4*)src)[tid + 256];
  }
  __syncthreads();

  const int col = tid;
  for(int n = 0; n < 32; ++n){
    const float* hrow = hidl + n*64;
    float acc = bias[col];
#pragma unroll
    for(int u = 0; u < 8; ++u){
      int bo = col*128 + ((u*16) ^ ((col & 7) << 4));
      bf16x8 wv = *(const bf16x8*)((const char*)WT + bo);
#pragma unroll
      for(int i = 0; i < 8; ++i) acc += hrow[u*8 + i] * bf2f(wv[i]);
    }
    P[(((size_t)b*N_ + nbase + n) << 8) + col] = (unsigned short)f2bf(acc);
  }
}

// ---------------- edge-MLP message passing (GEMM2 only, MFMA) --------------
// Round-7 structure (2 barriers/tile, loads consumed in-region).
__launch_bounds__(256, 6)
__global__ void k_msg(const unsigned short* __restrict__ P,
                      const float* __restrict__ W2, const float* __restrict__ b2,
                      const int* __restrict__ recvE, const int* __restrict__ sendE,
                      const unsigned short* __restrict__ perm2,
                      const int* __restrict__ stt, const float* __restrict__ deg,
                      float* __restrict__ agg, int layer){
  __shared__ __align__(16) short m1_lds[64 * 64];   // [e][h] bf16, XOR-swizzled
  __shared__ float acc[8][64];
  __shared__ float b2_lds[128];
  __shared__ short rl_lds[64];

  const int tid  = threadIdx.x;
  const int w    = tid >> 6, lane = tid & 63;
  const int l15  = lane & 15, l4 = lane >> 4;
  const int b    = blockIdx.y;
  const int nodeBase = blockIdx.x * 8;

  const float* W2k = W2 + layer * (T_ * H_ * H_);

  if(tid < 128) b2_lds[tid] = b2[layer*128 + tid];
  acc[tid >> 6][tid & 63] = 0.0f;
  { int t2 = tid + 256; acc[t2 >> 6][t2 & 63] = 0.0f; }

  // Both types' B fragments for GEMM2, 16 output columns per wave.
  bf16x8 B2f[2][2];
#pragma unroll
  for(int t = 0; t < 2; ++t)
#pragma unroll
    for(int ks = 0; ks < 2; ++ks){
      const float* p = W2k + (t*64 + w*16 + l15)*64 + ks*32 + l4*8;
      B2f[t][ks] = pack8(*(const f32x4*)p, *(const f32x4*)(p+4));
    }

  const int gcol = w*16 + l15;
  const unsigned short* permB = perm2 + (size_t)b * E_;
  const int* sttB = stt + b*2*513;

#pragma unroll
  for(int seg = 0; seg < 2; ++seg){
    const int s0 = sttB[seg*513 + nodeBase];
    const int s1 = sttB[seg*513 + nodeBase + 8];
    const int ntiles = (s1 - s0 + 63) >> 6;
    for(int it = 0; it < ntiles; ++it){
      const int sbase = s0 + it*64;
      { // ---- stage m1 = tanh(P_r[recv] + P_s[send]); 4 thr/edge, 16 h each
        int el = tid >> 2, part = tid & 3;
        int s = sbase + el;
        int h0 = part * 16;
        int bo0 = el*128 + ((h0*2)      ^ ((el & 7) << 4));
        int bo1 = el*128 + ((h0*2 + 16) ^ ((el & 7) << 4));
        if(s < s1){
          int eid = permB[s];
          int rv = recvE[eid], sd = sendE[eid];
          if(part == 0) rl_lds[el] = (short)(rv - nodeBase);
          const unsigned short* pr = P + (((size_t)b*N_ + rv) << 8) + seg*64 + h0;
          const unsigned short* ps = P + (((size_t)b*N_ + sd) << 8) + (2+seg)*64 + h0;
          u32x4 R0 = *(const u32x4*)pr, R1 = *(const u32x4*)(pr + 8);
          u32x4 S0 = *(const u32x4*)ps, S1 = *(const u32x4*)(ps + 8);
          unsigned q0[4], q1[4];
#pragma unroll
          for(int j = 0; j < 4; ++j){
            unsigned t0 = (unsigned)(unsigned short)f2bf(fast_tanh(lo16f(R0[j]) + lo16f(S0[j])));
            unsigned t1 = (unsigned)(unsigned short)f2bf(fast_tanh(hi16f(R0[j]) + hi16f(S0[j])));
            q0[j] = t0 | (t1 << 16);
            unsigned t2 = (unsigned)(unsigned short)f2bf(fast_tanh(lo16f(R1[j]) + lo16f(S1[j])));
            unsigned t3 = (unsigned)(unsigned short)f2bf(fast_tanh(hi16f(R1[j]) + hi16f(S1[j])));
            q1[j] = t2 | (t3 << 16);
          }
          *(u32x4*)((char*)m1_lds + bo0) = (u32x4){q0[0], q0[1], q0[2], q0[3]};
          *(u32x4*)((char*)m1_lds + bo1) = (u32x4){q1[0], q1[1], q1[2], q1[3]};
        }else{
          if(part == 0) rl_lds[el] = 255;
          u32x4 z = {};
          *(u32x4*)((char*)m1_lds + bo0) = z;
          *(u32x4*)((char*)m1_lds + bo1) = z;
        }
      }
      __syncthreads();

      // ---- GEMM2 (16 cols/wave, type = seg), K=64
      f32x4 C2[4];
      { float bv = b2_lds[seg*64 + gcol];
#pragma unroll
        for(int ef = 0; ef < 4; ++ef) C2[ef] = (f32x4){bv, bv, bv, bv}; }
#pragma unroll
      for(int ks = 0; ks < 2; ++ks){
#pragma unroll
        for(int ef = 0; ef < 4; ++ef){
          int e = ef*16 + l15;
          int byteoff = e*128 + (((ks*32 + l4*8)*2) ^ ((e & 7) << 4));
          bf16x8 A = *(const bf16x8*)((const char*)m1_lds + byteoff);
          C2[ef] = __builtin_amdgcn_mfma_f32_16x16x32_bf16(A, B2f[seg][ks], C2[ef], 0, 0, 0);
        }
      }
      // ---- tanh, run-merge by rl (sorted within segment), LDS accumulate
      {
        int prl = -1; float pend = 0.f;
#pragma unroll
        for(int ef = 0; ef < 4; ++ef){
          s16x4 rl4 = *(const s16x4*)&rl_lds[ef*16 + l4*4];
#pragma unroll
          for(int r = 0; r < 4; ++r){
            int rl = rl4[r];
            if(rl != prl){
              if(prl >= 0) atomicAdd(&acc[prl][gcol], pend);
              pend = 0.f;
              prl = (rl == 255) ? -1 : rl;
            }
            if(rl != 255) pend += fast_tanh(C2[ef][r]);
          }
        }
        if(prl >= 0) atomicAdd(&acc[prl][gcol], pend);
      }
      __syncthreads();
    }
  }

  // ---- final: agg[b][node][g] = acc * 0.5 / deg   (0.5 = 1/T norm folded)
#pragma unroll
  for(int q = 0; q < 2; ++q){
    int idx = tid + q*256;
    int rl = idx >> 6, g = idx & 63;
    int node = nodeBase + rl;
    agg[(((size_t)b*N_ + node) << 6) + g] = acc[rl][g] * 0.5f / deg[node];
  }
}

// ---------------- GRU-style node update (32 ids/block) ---------------------
__launch_bounds__(256, 2)
__global__ void k_gru(const float* __restrict__ x, const float* __restrict__ hid,
                      const float* __restrict__ agg0, const float* __restrict__ agg1,
                      const float* __restrict__ Whr, const float* __restrict__ Whi,
                      const float* __restrict__ Whh,
                      const float* __restrict__ Wir, const float* __restrict__ bir,
                      const float* __restrict__ Wii, const float* __restrict__ bii,
                      const float* __restrict__ Win, const float* __restrict__ binw,
                      float* __restrict__ hnew){
  __shared__ short WhrT[128*64], WhiT[128*64], WhhT[128*64];  // [f][g] bf16
  __shared__ float WxT[3][8*64];                              // [j][g]
  __shared__ float bias[3][64];
  __shared__ float agg_lds[4][128];

  int tid = threadIdx.x;
  for(int s = tid; s < 8192; s += 256){
    int g = s >> 7, f = s & 127;
    WhrT[f*64+g] = f2bf(Whr[s]);
    WhiT[f*64+g] = f2bf(Whi[s]);
    WhhT[f*64+g] = f2bf(Whh[s]);
  }
  for(int s = tid; s < 512; s += 256){
    int g = s >> 3, j = s & 7;
    WxT[0][j*64+g] = Wir[s]; WxT[1][j*64+g] = Wii[s]; WxT[2][j*64+g] = Win[s];
  }
  if(tid < 64){ bias[0][tid] = bir[tid]; bias[1][tid] = bii[tid]; bias[2][tid] = binw[tid]; }
  __syncthreads();

  int w = tid >> 6, lane = tid & 63;
  for(int j = 0; j < 8; ++j){
    int id = blockIdx.x*32 + j*4 + w;        // [0, B*N)
    size_t base = (size_t)id * 64;
    agg_lds[w][lane]      = agg0[base + lane];  // wave-local, no barrier needed
    agg_lds[w][64 + lane] = agg1[base + lane];

    float ar = bias[0][lane], ai = bias[1][lane], an = bias[2][lane], ah = 0.f;
    const float* xp = x + (size_t)id * 8;
#pragma unroll
    for(int jj = 0; jj < 8; ++jj){
      float xv = xp[jj];
      ar += xv * WxT[0][jj*64+lane];
      ai += xv * WxT[1][jj*64+lane];
      an += xv * WxT[2][jj*64+lane];
    }
#pragma unroll 4
    for(int f = 0; f < 128; ++f){
      float av = agg_lds[w][f];
      ar += av * bf2f(WhrT[f*64+lane]);
      ai += av * bf2f(WhiT[f*64+lane]);
      ah += av * bf2f(WhhT[f*64+lane]);
    }
    float r  = fast_sigm(ar);
    float ii = fast_sigm(ai);
    float ng = fast_tanh(an + r * ah);
    float ho = hid[base + lane];
    hnew[base + lane] = (1.0f - ii) * ng + ii * ho;
  }
}

// ---------------- pred = Wm2 @ relu(Wm1 @ hnew + bm1) + bm2 (32 ids/block) -
// writes flat as bf16 [B][32768]
__launch_bounds__(256, 2)
__global__ void k_pred(const float* __restrict__ hnew,
                       const float* __restrict__ Wm1, const float* __restrict__ bm1,
                       const float* __restrict__ Wm2, const float* __restrict__ bm2,
                       unsigned short* __restrict__ flatbf){
  __shared__ float W1T[64*64], W2T[64*64];   // [h][g]
  __shared__ float bias1[64], bias2[64];
  __shared__ float h_lds[4][64], t_lds[4][64];
  int tid = threadIdx.x;
  for(int s = tid; s < 4096; s += 256){
    int g = s >> 6, h = s & 63;
    W1T[h*64+g] = Wm1[s];
    W2T[h*64+g] = Wm2[s];
  }
  if(tid < 64){ bias1[tid] = bm1[tid]; bias2[tid] = bm2[tid]; }
  __syncthreads();

  int w = tid >> 6, lane = tid & 63;
  for(int j = 0; j < 8; ++j){
    int id = blockIdx.x*32 + j*4 + w;
    size_t base = (size_t)id * 64;
    h_lds[w][lane] = hnew[base + lane];
    float a = bias1[lane];
#pragma unroll 4
    for(int h = 0; h < 64; ++h) a += h_lds[w][h] * W1T[h*64+lane];
    a = fmaxf(a, 0.0f);
    t_lds[w][lane] = a;
    float p = bias2[lane];
#pragma unroll 4
    for(int h = 0; h < 64; ++h) p += t_lds[w][h] * W2T[h*64+lane];
    flatbf[base + lane] = (unsigned short)f2bf(p);   // flat[b][n*64+g] bf16
  }
}

// ---------------- k_out: pacc[1536][32] += W[mt]·flat^T, split-K MFMA ------
__launch_bounds__(256, 6)
__global__ void k_out(const float* __restrict__ Wdf, const float* __restrict__ Wloc,
                      const float* __restrict__ Wsc,
                      const unsigned short* __restrict__ flatbf,
                      float* __restrict__ pacc){
  const int bid = blockIdx.x;
  const int mt  = bid >> 5;                  // [0,48) M-tile of 32 rows
  const int kb  = bid & 31;                  // K-chunk of 1024
  const int row0 = mt * 32;                  // global row in [0,1536)
  const int mat  = row0 >> 9;
  const int rloc = row0 & 511;
  const float* W = (mat == 0) ? Wdf : (mat == 1) ? Wloc : Wsc;

  const int tid = threadIdx.x, w = tid >> 6, lane = tid & 63;
  const int l15 = lane & 15, l4 = lane >> 4;
  const float* wp = W + (size_t)(rloc + (w & 1)*16 + l15)*32768 + kb*1024 + l4*8;
  const unsigned short* fp = flatbf + (size_t)((w >> 1)*16 + l15)*32768 + kb*1024 + l4*8;

  f32x4 acc0 = {}, acc1 = {};
#pragma unroll 4
  for(int ks = 0; ks < 32; ks += 2){
    f32x4 a0 = *(const f32x4*)(wp + ks*32);
    f32x4 a1 = *(const f32x4*)(wp + ks*32 + 4);
    bf16x8 Bv0 = *(const bf16x8*)(fp + ks*32);
    f32x4 a2 = *(const f32x4*)(wp + ks*32 + 32);
    f32x4 a3 = *(const f32x4*)(wp + ks*32 + 36);
    bf16x8 Bv1 = *(const bf16x8*)(fp + ks*32 + 32);
    acc0 = __builtin_amdgcn_mfma_f32_16x16x32_bf16(pack8cvt(a0, a1), Bv0, acc0, 0, 0, 0);
    acc1 = __builtin_amdgcn_mfma_f32_16x16x32_bf16(pack8cvt(a2, a3), Bv1, acc1, 0, 0, 0);
  }
  // C/D: col = l15 (batch), row = l4*4 + r (within 16-row half-tile)
#pragma unroll
  for(int r = 0; r < 4; ++r){
    int grow = row0 + (w & 1)*16 + l4*4 + r;
    atomicAdd(&pacc[grow*32 + (w >> 1)*16 + l15], acc0[r] + acc1[r]);
  }
}

// ---------------- k_fin: bias + StudentT transforms ------------------------
__global__ void k_fin(const float* __restrict__ pacc,
                      const float* __restrict__ bdf, const float* __restrict__ bloc,
                      const float* __restrict__ bsc, float* __restrict__ out){
  int i = blockIdx.x*256 + threadIdx.x;      // [0, 49152)
  int mat = i >> 14;
  int rem = i & 16383;                       // b*512 + og
  int b = rem >> 9, og = rem & 511;
  float s = pacc[(mat*512 + og)*32 + b];
  s += (mat == 0 ? bdf : mat == 1 ? bloc : bsc)[og];
  float res = (mat == 0) ? 2.0f + softplus_f(s) : (mat == 1) ? s : softplus_f(s);
  out[i] = res;
}

extern "C" void kernel_launch(void* const* d_in, const int* in_sizes, int n_in,
                              void* d_out, int out_size, void* d_ws, size_t ws_size,
                              hipStream_t stream){
  (void)in_sizes; (void)n_in; (void)out_size; (void)ws_size;
  const float* inputs = (const float*)d_in[0];
  const float* hidden = (const float*)d_in[1];
  const float* elog   = (const float*)d_in[2];
  const float* gum    = (const float*)d_in[3];
  const int*   sendE  = (const int*)  d_in[4];
  const int*   recvE  = (const int*)  d_in[5];
  const float* W1   = (const float*)d_in[6];
  const float* b1   = (const float*)d_in[7];
  const float* W2   = (const float*)d_in[8];
  const float* b2   = (const float*)d_in[9];
  const float* Whr  = (const float*)d_in[10];
  const float* Whi  = (const float*)d_in[11];
  const float* Whh  = (const float*)d_in[12];
  const float* Wir  = (const float*)d_in[13]; const float* bir  = (const float*)d_in[14];
  const float* Wii  = (const float*)d_in[15]; const float* bii  = (const float*)d_in[16];
  const float* Win  = (const float*)d_in[17]; const float* binw = (const float*)d_in[18];
  const float* Wm1  = (const float*)d_in[19]; const float* bm1  = (const float*)d_in[20];
  const float* Wm2  = (const float*)d_in[21]; const float* bm2  = (const float*)d_in[22];
  const float* Wdf  = (const float*)d_in[23]; const float* bdf  = (const float*)d_in[24];
  const float* Wloc = (const float*)d_in[25]; const float* bloc = (const float*)d_in[26];
  const float* Wsc  = (const float*)d_in[27]; const float* bsc  = (const float*)d_in[28];

  float* out       = (float*)d_out;
  float* out_hid   = out + 49152;            // df,loc,scale = 3*16384
  float* out_edges = out + 1097728;          // + B*N*H

  char* ws = (char*)d_ws;
  float* agg0 = (float*)(ws);                               // 4 MB
  float* agg1 = (float*)(ws + 4194304);                     // 4 MB
  unsigned short* P = (unsigned short*)(ws + 8388608);      // 8 MB [B][N][4][64] bf16
  unsigned short* flatbf = (unsigned short*)(ws + 8388608); // 2 MB overlay on P (after k_msg)
  unsigned short* perm2 = (unsigned short*)(ws + 16777216); // 2 MB [B][E]
  unsigned char* typ = (unsigned char*)(ws + 18874368);     // 1 MB [B][E]
  int*   hist      = (int*)(ws + 19922944);                 // 2 KB
  int*   row_start = (int*)(ws + 19924992);                 // 4 KB slot (513 ints)
  float* deg       = (float*)(ws + 19929088);               // 2 KB
  int*   n0        = (int*)(ws + 19931136);                 // 64 KB [B][512]
  int*   cur0      = (int*)(ws + 19996672);                 // 64 KB
  int*   cur1      = (int*)(ws + 20062208);                 // 64 KB
  int*   stt       = (int*)(ws + 20127744);                 // 128.25 KB [B][2][513]
  float* pacc      = agg0;                                  // 196 KB overlay (agg0 dead after k_gru)

  hipMemsetAsync(hist, 0, 2048, stream);
  hipMemsetAsync(n0, 0, 3*65536, stream);    // n0, cur0, cur1 contiguous

  k_edges<<<4096, 256, 0, stream>>>(elog, gum, out_edges, typ);
  k_hist<<<128, 256, 0, stream>>>(recvE, hist);
  k_scan<<<1, 512, 0, stream>>>(hist, row_start, deg);
  k_hist2<<<dim3(16, 32), 256, 0, stream>>>(recvE, typ, n0);
  k_scan2<<<32, 512, 0, stream>>>(n0, row_start, stt);
  k_perm2<<<4096, 256, 0, stream>>>(recvE, typ, stt, cur0, cur1, perm2);

  k_prep<<<dim3(16, 32), 256, 0, stream>>>(hidden, W1, b1, P, 0);
  k_msg<<<dim3(64, 32), 256, 0, stream>>>(P, W2, b2, recvE, sendE,
                                          perm2, stt, deg, agg0, 0);
  k_prep<<<dim3(16, 32), 256, 0, stream>>>(agg0, W1, b1, P, 1);
  k_msg<<<dim3(64, 32), 256, 0, stream>>>(P, W2, b2, recvE, sendE,
                                          perm2, stt, deg, agg1, 1);

  k_gru<<<512, 256, 0, stream>>>(inputs, hidden, agg0, agg1,
                                 Whr, Whi, Whh, Wir, bir, Wii, bii, Win, binw, out_hid);
  k_pred<<<512, 256, 0, stream>>>(out_hid, Wm1, bm1, Wm2, bm2, flatbf);
  hipMemsetAsync(pacc, 0, 1536*32*4, stream);   // agg0 dead after k_gru
  k_out<<<1536, 256, 0, stream>>>(Wdf, Wloc, Wsc, flatbf, pacc);
  k_fin<<<192, 256, 0, stream>>>(pacc, bdf, bloc, bsc, out);
}

// Round 11
// 465.696 us; speedup vs baseline: 1.7471x; 1.0385x over previous
//
#include <hip/hip_runtime.h>

#define B_  32
#define N_  512
#define E_  32768
#define H_  64
#define L_  2
#define T_  2
#define IN_ 8

typedef __attribute__((ext_vector_type(4))) float f32x4;
typedef __attribute__((ext_vector_type(8))) short bf16x8;
typedef __attribute__((ext_vector_type(4))) short s16x4;
typedef __attribute__((ext_vector_type(4))) unsigned u32x4;

__device__ __forceinline__ short f2bf(float f){
  unsigned u = __float_as_uint(f);
  u += 0x7FFFu + ((u >> 16) & 1u);          // RNE round to bf16
  return (short)(u >> 16);
}
__device__ __forceinline__ float bf2f(short s){
  return __uint_as_float(((unsigned)(unsigned short)s) << 16);
}
__device__ __forceinline__ bf16x8 pack8(f32x4 a, f32x4 b){
  bf16x8 r;
  r[0]=f2bf(a[0]); r[1]=f2bf(a[1]); r[2]=f2bf(a[2]); r[3]=f2bf(a[3]);
  r[4]=f2bf(b[0]); r[5]=f2bf(b[1]); r[6]=f2bf(b[2]); r[7]=f2bf(b[3]);
  return r;
}
__device__ __forceinline__ unsigned cvt_pk_bf16(float lo, float hi){
  unsigned r;
  asm("v_cvt_pk_bf16_f32 %0, %1, %2" : "=v"(r) : "v"(lo), "v"(hi));
  return r;
}
__device__ __forceinline__ bf16x8 pack8cvt(f32x4 a, f32x4 b){
  union { u32x4 u; bf16x8 h; } r;
  r.u[0] = cvt_pk_bf16(a[0], a[1]);
  r.u[1] = cvt_pk_bf16(a[2], a[3]);
  r.u[2] = cvt_pk_bf16(b[0], b[1]);
  r.u[3] = cvt_pk_bf16(b[2], b[3]);
  return r.h;
}
__device__ __forceinline__ float lo16f(unsigned u){ return __uint_as_float(u << 16); }
__device__ __forceinline__ float hi16f(unsigned u){ return __uint_as_float(u & 0xffff0000u); }

__device__ __forceinline__ float fast_tanh(float x){
  float e = __builtin_amdgcn_exp2f(x * 2.8853900817779268f);  // e^(2x)
  float r = __builtin_amdgcn_rcpf(e + 1.0f);
  return __builtin_fmaf(-2.0f, r, 1.0f);
}
__device__ __forceinline__ float fast_sigm(float x){
  return __builtin_amdgcn_rcpf(1.0f + __builtin_amdgcn_exp2f(x * -1.4426950408889634f));
}
__device__ __forceinline__ float softplus_f(float x){
  return fmaxf(x, 0.0f) + log1pf(__expf(-fabsf(x)));
}

// ---------------- edges: hard gumbel-softmax (forward value == one-hot) ----
__global__ void k_edges(const float* __restrict__ logits, const float* __restrict__ gum,
                        float* __restrict__ edges_out, unsigned char* __restrict__ type_out){
  int i = blockIdx.x * 256 + threadIdx.x;   // [0, B*E)
  if(i >= B_ * E_) return;
  float l0 = logits[2*i]   + gum[2*i];
  float l1 = logits[2*i+1] + gum[2*i+1];
  int t = (l1 > l0) ? 1 : 0;                // argmax, first-wins on tie
  edges_out[2*i]   = t ? 0.f : 1.f;
  edges_out[2*i+1] = t ? 1.f : 0.f;
  type_out[i] = (unsigned char)t;
}

// ---------------- batch-independent recv CSR (row_start, deg) --------------
__global__ void k_hist(const int* __restrict__ recvE, int* __restrict__ hist){
  int e = blockIdx.x * 256 + threadIdx.x;
  if(e < E_) atomicAdd(&hist[recvE[e]], 1);
}
__global__ void k_scan(const int* __restrict__ hist, int* __restrict__ row_start,
                       float* __restrict__ deg){
  __shared__ int a[512], bbuf[512];
  int t = threadIdx.x;
  int h = hist[t];
  a[t] = h;
  __syncthreads();
  int* cur = a; int* nxt = bbuf;
  for(int off = 1; off < 512; off <<= 1){
    int v = cur[t] + (t >= off ? cur[t - off] : 0);
    nxt[t] = v;
    __syncthreads();
    int* tmp = cur; cur = nxt; nxt = tmp;
  }
  row_start[t] = cur[t] - h;                // exclusive
  if(t == 0) row_start[512] = E_;
  deg[t] = (h == 0) ? 1.0f : (float)h;
}

// ---------------- per-batch (type, recv) CSR build -------------------------
__global__ void k_hist2(const int* __restrict__ recvE, const unsigned char* __restrict__ typ,
                        int* __restrict__ n0){
  __shared__ int lh[512];
  int b = blockIdx.y, tid = threadIdx.x;
  lh[tid] = 0; lh[tid + 256] = 0;
  __syncthreads();
  int e0 = blockIdx.x * 2048;
  for(int k = 0; k < 8; ++k){
    int e = e0 + k*256 + tid;
    if(typ[(size_t)b*E_ + e] == 0) atomicAdd(&lh[recvE[e]], 1);
  }
  __syncthreads();
  if(lh[tid])       atomicAdd(&n0[b*512 + tid],       lh[tid]);
  if(lh[tid + 256]) atomicAdd(&n0[b*512 + tid + 256], lh[tid + 256]);
}
__global__ void k_scan2(const int* __restrict__ n0, const int* __restrict__ row_start,
                        int* __restrict__ stt){
  __shared__ int a[512], bbuf[512];
  __shared__ int tot;
  int b = blockIdx.x, t = threadIdx.x;
  int h = n0[b*512 + t];
  a[t] = h;
  __syncthreads();
  int* cur = a; int* nxt = bbuf;
  for(int off = 1; off < 512; off <<= 1){
    int v = cur[t] + (t >= off ? cur[t - off] : 0);
    nxt[t] = v;
    __syncthreads();
    int* tmp = cur; cur = nxt; nxt = tmp;
  }
  if(t == 511) tot = cur[511];
  __syncthreads();
  int excl = cur[t] - h;
  stt[(b*2    )*513 + t] = excl;                       // type-0 run start
  stt[(b*2 + 1)*513 + t] = tot + row_start[t] - excl;  // type-1 run start
  if(t == 0){ stt[(b*2)*513 + 512] = tot; stt[(b*2+1)*513 + 512] = E_; }
}
__global__ void k_perm2(const int* __restrict__ recvE, const unsigned char* __restrict__ typ,
                        const int* __restrict__ stt, int* __restrict__ cur0,
                        int* __restrict__ cur1, unsigned short* __restrict__ perm2){
  int i = blockIdx.x * 256 + threadIdx.x;   // [0, B*E)
  int b = i >> 15, e = i & (E_ - 1);
  int r = recvE[e];
  int pos;
  if(typ[i] == 0) pos = stt[(b*2  )*513 + r] + atomicAdd(&cur0[b*512 + r], 1);
  else            pos = stt[(b*2+1)*513 + r] + atomicAdd(&cur1[b*512 + r], 1);
  perm2[(size_t)b*E_ + pos] = (unsigned short)e;
}

// ---------------- per-node GEMM1 hoist ------------------------------------
// P[b][n][slot][64] bf16, slot = {t0_recv(+b1), t1_recv(+b1), t0_send, t1_send}
__launch_bounds__(256, 2)
__global__ void k_prep(const float* __restrict__ hid,
                       const float* __restrict__ W1, const float* __restrict__ b1,
                       unsigned short* __restrict__ P, int layer){
  __shared__ __align__(16) short WT[256 * 64];   // [col][f] bf16, XOR-swizzled
  __shared__ float bias[256];
  __shared__ float hidl[32 * 64];                // 32 nodes staged f32 (8 KB)

  const int tid = threadIdx.x;
  const int b   = blockIdx.y;
  const int nbase = blockIdx.x * 32;
  const float* W1k = W1 + layer * (T_ * H_ * 2 * H_);

  { // stage WT: col = tid -> slot = col>>6, h = col&63; src W1k[t][h][prt*64 + f]
    int col = tid, slot = col >> 6, h = col & 63;
    int t = slot & 1, prt = slot >> 1;
    const float* src = W1k + t*8192 + h*128 + prt*64;
#pragma unroll
    for(int u = 0; u < 8; ++u){
      bf16x8 v = pack8(*(const f32x4*)(src + u*8), *(const f32x4*)(src + u*8 + 4));
      int bo = col*128 + ((u*16) ^ ((col & 7) << 4));
      *(bf16x8*)((char*)WT + bo) = v;
    }
    bias[col] = (slot < 2) ? b1[layer*128 + t*64 + h] : 0.0f;
  }
  { // stage 32 nodes of hid: 2048 f32 = 512 f32x4, 2 per thread
    const float* src = hid + ((size_t)b*N_ + nbase)*H_;
    ((f32x4*)hidl)[tid]       = ((const f32x4*)src)[tid];
    ((f32x4*)hidl)[tid + 256] = ((const f32x4*)src)[tid + 256];
  }
  __syncthreads();

  const int col = tid;
  for(int n = 0; n < 32; ++n){
    const float* hrow = hidl + n*64;
    float acc = bias[col];
#pragma unroll
    for(int u = 0; u < 8; ++u){
      int bo = col*128 + ((u*16) ^ ((col & 7) << 4));
      bf16x8 wv = *(const bf16x8*)((const char*)WT + bo);
#pragma unroll
      for(int i = 0; i < 8; ++i) acc += hrow[u*8 + i] * bf2f(wv[i]);
    }
    P[(((size_t)b*N_ + nbase + n) << 8) + col] = (unsigned short)f2bf(acc);
  }
}

// ---------------- edge-MLP message passing (GEMM2 only, MFMA) --------------
// Round-7 structure (2 barriers/tile, loads consumed in-region).
// launch_bounds(256,8): 2048 blocks = 8/CU x 256 CU -> whole grid co-resident
// in ONE dispatch round (kills the 512-block tail that capped occupancy ~45%).
__launch_bounds__(256, 8)
__global__ void k_msg(const unsigned short* __restrict__ P,
                      const float* __restrict__ W2, const float* __restrict__ b2,
                      const int* __restrict__ recvE, const int* __restrict__ sendE,
                      const unsigned short* __restrict__ perm2,
                      const int* __restrict__ stt, const float* __restrict__ deg,
                      float* __restrict__ agg, int layer){
  __shared__ __align__(16) short m1_lds[64 * 64];   // [e][h] bf16, XOR-swizzled
  __shared__ float acc[8][64];
  __shared__ float b2_lds[128];
  __shared__ short rl_lds[64];

  const int tid  = threadIdx.x;
  const int w    = tid >> 6, lane = tid & 63;
  const int l15  = lane & 15, l4 = lane >> 4;
  const int b    = blockIdx.y;
  const int nodeBase = blockIdx.x * 8;

  const float* W2k = W2 + layer * (T_ * H_ * H_);

  if(tid < 128) b2_lds[tid] = b2[layer*128 + tid];
  acc[tid >> 6][tid & 63] = 0.0f;
  { int t2 = tid + 256; acc[t2 >> 6][t2 & 63] = 0.0f; }

  // Both types' B fragments for GEMM2, 16 output columns per wave.
  bf16x8 B2f[2][2];
#pragma unroll
  for(int t = 0; t < 2; ++t)
#pragma unroll
    for(int ks = 0; ks < 2; ++ks){
      const float* p = W2k + (t*64 + w*16 + l15)*64 + ks*32 + l4*8;
      B2f[t][ks] = pack8(*(const f32x4*)p, *(const f32x4*)(p+4));
    }

  const int gcol = w*16 + l15;
  const unsigned short* permB = perm2 + (size_t)b * E_;
  const int* sttB = stt + b*2*513;

#pragma unroll
  for(int seg = 0; seg < 2; ++seg){
    const int s0 = sttB[seg*513 + nodeBase];
    const int s1 = sttB[seg*513 + nodeBase + 8];
    const int ntiles = (s1 - s0 + 63) >> 6;
    for(int it = 0; it < ntiles; ++it){
      const int sbase = s0 + it*64;
      { // ---- stage m1 = tanh(P_r[recv] + P_s[send]); 4 thr/edge, 16 h each
        int el = tid >> 2, part = tid & 3;
        int s = sbase + el;
        int h0 = part * 16;
        int bo0 = el*128 + ((h0*2)      ^ ((el & 7) << 4));
        int bo1 = el*128 + ((h0*2 + 16) ^ ((el & 7) << 4));
        if(s < s1){
          int eid = permB[s];
          int rv = recvE[eid], sd = sendE[eid];
          if(part == 0) rl_lds[el] = (short)(rv - nodeBase);
          const unsigned short* pr = P + (((size_t)b*N_ + rv) << 8) + seg*64 + h0;
          const unsigned short* ps = P + (((size_t)b*N_ + sd) << 8) + (2+seg)*64 + h0;
          u32x4 R0 = *(const u32x4*)pr, R1 = *(const u32x4*)(pr + 8);
          u32x4 S0 = *(const u32x4*)ps, S1 = *(const u32x4*)(ps + 8);
          unsigned q0[4], q1[4];
#pragma unroll
          for(int j = 0; j < 4; ++j){
            q0[j] = cvt_pk_bf16(fast_tanh(lo16f(R0[j]) + lo16f(S0[j])),
                                fast_tanh(hi16f(R0[j]) + hi16f(S0[j])));
            q1[j] = cvt_pk_bf16(fast_tanh(lo16f(R1[j]) + lo16f(S1[j])),
                                fast_tanh(hi16f(R1[j]) + hi16f(S1[j])));
          }
          *(u32x4*)((char*)m1_lds + bo0) = (u32x4){q0[0], q0[1], q0[2], q0[3]};
          *(u32x4*)((char*)m1_lds + bo1) = (u32x4){q1[0], q1[1], q1[2], q1[3]};
        }else{
          if(part == 0) rl_lds[el] = 255;
          u32x4 z = {};
          *(u32x4*)((char*)m1_lds + bo0) = z;
          *(u32x4*)((char*)m1_lds + bo1) = z;
        }
      }
      __syncthreads();

      // ---- GEMM2 (16 cols/wave, type = seg), K=64
      f32x4 C2[4];
      { float bv = b2_lds[seg*64 + gcol];
#pragma unroll
        for(int ef = 0; ef < 4; ++ef) C2[ef] = (f32x4){bv, bv, bv, bv}; }
#pragma unroll
      for(int ks = 0; ks < 2; ++ks){
#pragma unroll
        for(int ef = 0; ef < 4; ++ef){
          int e = ef*16 + l15;
          int byteoff = e*128 + (((ks*32 + l4*8)*2) ^ ((e & 7) << 4));
          bf16x8 A = *(const bf16x8*)((const char*)m1_lds + byteoff);
          C2[ef] = __builtin_amdgcn_mfma_f32_16x16x32_bf16(A, B2f[seg][ks], C2[ef], 0, 0, 0);
        }
      }
      // ---- tanh, run-merge by rl (sorted within segment), LDS accumulate
      {
        int prl = -1; float pend = 0.f;
#pragma unroll
        for(int ef = 0; ef < 4; ++ef){
          s16x4 rl4 = *(const s16x4*)&rl_lds[ef*16 + l4*4];
#pragma unroll
          for(int r = 0; r < 4; ++r){
            int rl = rl4[r];
            if(rl != prl){
              if(prl >= 0) atomicAdd(&acc[prl][gcol], pend);
              pend = 0.f;
              prl = (rl == 255) ? -1 : rl;
            }
            if(rl != 255) pend += fast_tanh(C2[ef][r]);
          }
        }
        if(prl >= 0) atomicAdd(&acc[prl][gcol], pend);
      }
      __syncthreads();
    }
  }

  // ---- final: agg[b][node][g] = acc * 0.5 / deg   (0.5 = 1/T norm folded)
#pragma unroll
  for(int q = 0; q < 2; ++q){
    int idx = tid + q*256;
    int rl = idx >> 6, g = idx & 63;
    int node = nodeBase + rl;
    agg[(((size_t)b*N_ + node) << 6) + g] = acc[rl][g] * 0.5f / deg[node];
  }
}

// ---------------- GRU-style node update (32 ids/block) ---------------------
__launch_bounds__(256, 2)
__global__ void k_gru(const float* __restrict__ x, const float* __restrict__ hid,
                      const float* __restrict__ agg0, const float* __restrict__ agg1,
                      const float* __restrict__ Whr, const float* __restrict__ Whi,
                      const float* __restrict__ Whh,
                      const float* __restrict__ Wir, const float* __restrict__ bir,
                      const float* __restrict__ Wii, const float* __restrict__ bii,
                      const float* __restrict__ Win, const float* __restrict__ binw,
                      float* __restrict__ hnew){
  __shared__ short WhrT[128*64], WhiT[128*64], WhhT[128*64];  // [f][g] bf16
  __shared__ float WxT[3][8*64];                              // [j][g]
  __shared__ float bias[3][64];
  __shared__ float agg_lds[4][128];

  int tid = threadIdx.x;
  for(int s = tid; s < 8192; s += 256){
    int g = s >> 7, f = s & 127;
    WhrT[f*64+g] = f2bf(Whr[s]);
    WhiT[f*64+g] = f2bf(Whi[s]);
    WhhT[f*64+g] = f2bf(Whh[s]);
  }
  for(int s = tid; s < 512; s += 256){
    int g = s >> 3, j = s & 7;
    WxT[0][j*64+g] = Wir[s]; WxT[1][j*64+g] = Wii[s]; WxT[2][j*64+g] = Win[s];
  }
  if(tid < 64){ bias[0][tid] = bir[tid]; bias[1][tid] = bii[tid]; bias[2][tid] = binw[tid]; }
  __syncthreads();

  int w = tid >> 6, lane = tid & 63;
  for(int j = 0; j < 8; ++j){
    int id = blockIdx.x*32 + j*4 + w;        // [0, B*N)
    size_t base = (size_t)id * 64;
    agg_lds[w][lane]      = agg0[base + lane];  // wave-local, no barrier needed
    agg_lds[w][64 + lane] = agg1[base + lane];

    float ar = bias[0][lane], ai = bias[1][lane], an = bias[2][lane], ah = 0.f;
    const float* xp = x + (size_t)id * 8;
#pragma unroll
    for(int jj = 0; jj < 8; ++jj){
      float xv = xp[jj];
      ar += xv * WxT[0][jj*64+lane];
      ai += xv * WxT[1][jj*64+lane];
      an += xv * WxT[2][jj*64+lane];
    }
#pragma unroll 4
    for(int f = 0; f < 128; ++f){
      float av = agg_lds[w][f];
      ar += av * bf2f(WhrT[f*64+lane]);
      ai += av * bf2f(WhiT[f*64+lane]);
      ah += av * bf2f(WhhT[f*64+lane]);
    }
    float r  = fast_sigm(ar);
    float ii = fast_sigm(ai);
    float ng = fast_tanh(an + r * ah);
    float ho = hid[base + lane];
    hnew[base + lane] = (1.0f - ii) * ng + ii * ho;
  }
}

// ---------------- pred = Wm2 @ relu(Wm1 @ hnew + bm1) + bm2 (32 ids/block) -
// writes flat as bf16 [B][32768]
__launch_bounds__(256, 2)
__global__ void k_pred(const float* __restrict__ hnew,
                       const float* __restrict__ Wm1, const float* __restrict__ bm1,
                       const float* __restrict__ Wm2, const float* __restrict__ bm2,
                       unsigned short* __restrict__ flatbf){
  __shared__ float W1T[64*64], W2T[64*64];   // [h][g]
  __shared__ float bias1[64], bias2[64];
  __shared__ float h_lds[4][64], t_lds[4][64];
  int tid = threadIdx.x;
  for(int s = tid; s < 4096; s += 256){
    int g = s >> 6, h = s & 63;
    W1T[h*64+g] = Wm1[s];
    W2T[h*64+g] = Wm2[s];
  }
  if(tid < 64){ bias1[tid] = bm1[tid]; bias2[tid] = bm2[tid]; }
  __syncthreads();

  int w = tid >> 6, lane = tid & 63;
  for(int j = 0; j < 8; ++j){
    int id = blockIdx.x*32 + j*4 + w;
    size_t base = (size_t)id * 64;
    h_lds[w][lane] = hnew[base + lane];
    float a = bias1[lane];
#pragma unroll 4
    for(int h = 0; h < 64; ++h) a += h_lds[w][h] * W1T[h*64+lane];
    a = fmaxf(a, 0.0f);
    t_lds[w][lane] = a;
    float p = bias2[lane];
#pragma unroll 4
    for(int h = 0; h < 64; ++h) p += t_lds[w][h] * W2T[h*64+lane];
    flatbf[base + lane] = (unsigned short)f2bf(p);   // flat[b][n*64+g] bf16
  }
}

// ---------------- k_out: pacc[1536][32] += W[mt]·flat^T, split-K MFMA ------
__launch_bounds__(256, 6)
__global__ void k_out(const float* __restrict__ Wdf, const float* __restrict__ Wloc,
                      const float* __restrict__ Wsc,
                      const unsigned short* __restrict__ flatbf,
                      float* __restrict__ pacc){
  const int bid = blockIdx.x;
  const int mt  = bid >> 5;                  // [0,48) M-tile of 32 rows
  const int kb  = bid & 31;                  // K-chunk of 1024
  const int row0 = mt * 32;                  // global row in [0,1536)
  const int mat  = row0 >> 9;
  const int rloc = row0 & 511;
  const float* W = (mat == 0) ? Wdf : (mat == 1) ? Wloc : Wsc;

  const int tid = threadIdx.x, w = tid >> 6, lane = tid & 63;
  const int l15 = lane & 15, l4 = lane >> 4;
  const float* wp = W + (size_t)(rloc + (w & 1)*16 + l15)*32768 + kb*1024 + l4*8;
  const unsigned short* fp = flatbf + (size_t)((w >> 1)*16 + l15)*32768 + kb*1024 + l4*8;

  f32x4 acc0 = {}, acc1 = {};
#pragma unroll 4
  for(int ks = 0; ks < 32; ks += 2){
    f32x4 a0 = *(const f32x4*)(wp + ks*32);
    f32x4 a1 = *(const f32x4*)(wp + ks*32 + 4);
    bf16x8 Bv0 = *(const bf16x8*)(fp + ks*32);
    f32x4 a2 = *(const f32x4*)(wp + ks*32 + 32);
    f32x4 a3 = *(const f32x4*)(wp + ks*32 + 36);
    bf16x8 Bv1 = *(const bf16x8*)(fp + ks*32 + 32);
    acc0 = __builtin_amdgcn_mfma_f32_16x16x32_bf16(pack8cvt(a0, a1), Bv0, acc0, 0, 0, 0);
    acc1 = __builtin_amdgcn_mfma_f32_16x16x32_bf16(pack8cvt(a2, a3), Bv1, acc1, 0, 0, 0);
  }
  // C/D: col = l15 (batch), row = l4*4 + r (within 16-row half-tile)
#pragma unroll
  for(int r = 0; r < 4; ++r){
    int grow = row0 + (w & 1)*16 + l4*4 + r;
    atomicAdd(&pacc[grow*32 + (w >> 1)*16 + l15], acc0[r] + acc1[r]);
  }
}

// ---------------- k_fin: bias + StudentT transforms ------------------------
__global__ void k_fin(const float* __restrict__ pacc,
                      const float* __restrict__ bdf, const float* __restrict__ bloc,
                      const float* __restrict__ bsc, float* __restrict__ out){
  int i = blockIdx.x*256 + threadIdx.x;      // [0, 49152)
  int mat = i >> 14;
  int rem = i & 16383;                       // b*512 + og
  int b = rem >> 9, og = rem & 511;
  float s = pacc[(mat*512 + og)*32 + b];
  s += (mat == 0 ? bdf : mat == 1 ? bloc : bsc)[og];
  float res = (mat == 0) ? 2.0f + softplus_f(s) : (mat == 1) ? s : softplus_f(s);
  out[i] = res;
}

extern "C" void kernel_launch(void* const* d_in, const int* in_sizes, int n_in,
                              void* d_out, int out_size, void* d_ws, size_t ws_size,
                              hipStream_t stream){
  (void)in_sizes; (void)n_in; (void)out_size; (void)ws_size;
  const float* inputs = (const float*)d_in[0];
  const float* hidden = (const float*)d_in[1];
  const float* elog   = (const float*)d_in[2];
  const float* gum    = (const float*)d_in[3];
  const int*   sendE  = (const int*)  d_in[4];
  const int*   recvE  = (const int*)  d_in[5];
  const float* W1   = (const float*)d_in[6];
  const float* b1   = (const float*)d_in[7];
  const float* W2   = (const float*)d_in[8];
  const float* b2   = (const float*)d_in[9];
  const float* Whr  = (const float*)d_in[10];
  const float* Whi  = (const float*)d_in[11];
  const float* Whh  = (const float*)d_in[12];
  const float* Wir  = (const float*)d_in[13]; const float* bir  = (const float*)d_in[14];
  const float* Wii  = (const float*)d_in[15]; const float* bii  = (const float*)d_in[16];
  const float* Win  = (const float*)d_in[17]; const float* binw = (const float*)d_in[18];
  const float* Wm1  = (const float*)d_in[19]; const float* bm1  = (const float*)d_in[20];
  const float* Wm2  = (const float*)d_in[21]; const float* bm2  = (const float*)d_in[22];
  const float* Wdf  = (const float*)d_in[23]; const float* bdf  = (const float*)d_in[24];
  const float* Wloc = (const float*)d_in[25]; const float* bloc = (const float*)d_in[26];
  const float* Wsc  = (const float*)d_in[27]; const float* bsc  = (const float*)d_in[28];

  float* out       = (float*)d_out;
  float* out_hid   = out + 49152;            // df,loc,scale = 3*16384
  float* out_edges = out + 1097728;          // + B*N*H

  char* ws = (char*)d_ws;
  float* agg0 = (float*)(ws);                               // 4 MB
  float* agg1 = (float*)(ws + 4194304);                     // 4 MB
  unsigned short* P = (unsigned short*)(ws + 8388608);      // 8 MB [B][N][4][64] bf16
  unsigned short* flatbf = (unsigned short*)(ws + 8388608); // 2 MB overlay on P (after k_msg)
  unsigned short* perm2 = (unsigned short*)(ws + 16777216); // 2 MB [B][E]
  unsigned char* typ = (unsigned char*)(ws + 18874368);     // 1 MB [B][E]
  int*   hist      = (int*)(ws + 19922944);                 // 2 KB
  int*   row_start = (int*)(ws + 19924992);                 // 4 KB slot (513 ints)
  float* deg       = (float*)(ws + 19929088);               // 2 KB
  int*   n0        = (int*)(ws + 19931136);                 // 64 KB [B][512]
  int*   cur0      = (int*)(ws + 19996672);                 // 64 KB
  int*   cur1      = (int*)(ws + 20062208);                 // 64 KB
  int*   stt       = (int*)(ws + 20127744);                 // 128.25 KB [B][2][513]
  float* pacc      = agg0;                                  // 196 KB overlay (agg0 dead after k_gru)

  hipMemsetAsync(hist, 0, 2048, stream);
  hipMemsetAsync(n0, 0, 3*65536, stream);    // n0, cur0, cur1 contiguous

  k_edges<<<4096, 256, 0, stream>>>(elog, gum, out_edges, typ);
  k_hist<<<128, 256, 0, stream>>>(recvE, hist);
  k_scan<<<1, 512, 0, stream>>>(hist, row_start, deg);
  k_hist2<<<dim3(16, 32), 256, 0, stream>>>(recvE, typ, n0);
  k_scan2<<<32, 512, 0, stream>>>(n0, row_start, stt);
  k_perm2<<<4096, 256, 0, stream>>>(recvE, typ, stt, cur0, cur1, perm2);

  k_prep<<<dim3(16, 32), 256, 0, stream>>>(hidden, W1, b1, P, 0);
  k_msg<<<dim3(64, 32), 256, 0, stream>>>(P, W2, b2, recvE, sendE,
                                          perm2, stt, deg, agg0, 0);
  k_prep<<<dim3(16, 32), 256, 0, stream>>>(agg0, W1, b1, P, 1);
  k_msg<<<dim3(64, 32), 256, 0, stream>>>(P, W2, b2, recvE, sendE,
                                          perm2, stt, deg, agg1, 1);

  k_gru<<<512, 256, 0, stream>>>(inputs, hidden, agg0, agg1,
                                 Whr, Whi, Whh, Wir, bir, Wii, bii, Win, binw, out_hid);
  k_pred<<<512, 256, 0, stream>>>(out_hid, Wm1, bm1, Wm2, bm2, flatbf);
  hipMemsetAsync(pacc, 0, 1536*32*4, stream);   // agg0 dead after k_gru
  k_out<<<1536, 256, 0, stream>>>(Wdf, Wloc, Wsc, flatbf, pacc);
  k_fin<<<192, 256, 0, stream>>>(pacc, bdf, bloc, bsc, out);
}